// Round 2
// baseline (341.907 us; speedup 1.0000x reference)
//
#include <hip/hip_runtime.h>
#include <math.h>

// ---------------------------------------------------------------------------
// EncoderGPECls: kNN(16) -> PCA curvature blend -> adaptive GPE embeddings
// xyz: [8,4096,3] f32  ->  out: [8,4096,128] f32
//
// R14 = LDS-broadcast streaming (R12) at 3 blocks/CU occupancy (R13's goal).
//   R13 post-mortem: global-L2 candidate streaming raised occupancy to 62%
//   but real VALU issue FELL (39%->36%) -- L2 latency (~200-300cy) with
//   depth-1 prefetch beats out the extra waves. LDS broadcast was right;
//   the 64KB resident tile (2 blocks/CU) was the real cap.
//   Fix: stage 2048-pt half-tiles (32KB) from the repacked L2 buffer,
//   scan each pass in 2 staged rounds. LDS = 32KB tile + 17.4KB arena
//   (u64 key publishes; merge round 1 split in 2 sub-steps so only 2
//   regions needed) = 50.2KB -> 3 blocks/CU x 8 waves = 24 waves/CU.
//   Keep R13's d2' premultiply (3 fma/candidate), direct unrolled LDS
//   reads (no prefetch movs), exact-ordering selection semantics.
//   __launch_bounds__(512,6) caps VGPR at 85; pass-2 unroll=4 keeps the
//   k17-live section under pressure.
//
// ws float layout:
//   [0, 32768)            curv per point
//   [32768, 131072)       rasig2 (3 SoA planes of 32768)
//   [131072, 132096)      curv partial sums [b][chunk] (8 x 128)
//   [132096, 132192)      per-batch raw sums as 48 DOUBLES
//   [132192, 263264)      repacked points: 8*4096 float4 (-2x,-2y,-2z,|c|^2)
// ---------------------------------------------------------------------------

#define NPTS 4096
#define KNN 17          // 16 neighbors + self (self contributes zero to sums)
#define BLKT 512        // 8 waves
#define QPB 32          // queries per block (lane L and L+32 share a query)
#define TILE 2048       // staged candidates per round (32 KB)
#define LCH 128         // candidates per lane per tile (2 tiles -> 256 total)
#define SCAP 17         // survivor slots per lane

#define WS_CURV  0
#define WS_RAS2  32768
#define WS_CSUM  131072
#define WS_STAT  132096
#define WS_PTS   132192

typedef unsigned long long ull;
#define SENT 0xFFFFFFFFFFFFFFFFULL

// THE single d2' definition: explicit fmaf chain, identical IEEE ops at every
// call site. c = (-2cx,-2cy,-2cz,|c|^2), q = original coords.
// d2'(c,q) = |c|^2 - 2 c.q = |c-q|^2 - |q|^2 (per-query constant offset ->
// identical ordering; can be negative). Self always ranks first.
__device__ __forceinline__ float d2p(float4 c, float qx, float qy, float qz) {
    return __builtin_fmaf(c.x, qx, __builtin_fmaf(c.y, qy,
           __builtin_fmaf(c.z, qz, c.w)));
}

// order-preserving u32 encoding of a (possibly negative) float
__device__ __forceinline__ unsigned encf(float f) {
    unsigned u = __float_as_uint(f);
    return u ^ (unsigned)(((int)u >> 31) | 0x80000000u);
}

// predicated replace-max insert of packed (enc(d2')<<32|idx) key
__device__ __forceinline__ void insertp(ull v, bool ins, ull (&md)[KNN],
                                        ull& maxv, int& maxp) {
#pragma unroll
    for (int k = 0; k < KNN; k++) {
        bool sel = ins && (k == maxp);
        md[k] = sel ? v : md[k];
    }
    maxv = md[0]; maxp = 0;
#pragma unroll
    for (int k = 1; k < KNN; k++) {
        bool g = md[k] > maxv;
        maxv = g ? md[k] : maxv;
        maxp = g ? k : maxp;
    }
}

// ---------------- 3x3 symmetric eigensolve (double, trig method) -----------
__device__ __forceinline__ float curv_from_cov(float c00, float c01, float c02,
                                               float c11, float c12, float c22) {
    double a00 = c00, a01 = c01, a02 = c02, a11 = c11, a12 = c12, a22 = c22;
    double tr = a00 + a11 + a22;
    double q  = tr * (1.0 / 3.0);
    double b00 = a00 - q, b11 = a11 - q, b22 = a22 - q;
    double p2 = b00 * b00 + b11 * b11 + b22 * b22
              + 2.0 * (a01 * a01 + a02 * a02 + a12 * a12);
    double lmin;
    if (p2 < 1e-60) {
        lmin = q;
    } else {
        double p  = sqrt(p2 * (1.0 / 6.0));
        double ip = 1.0 / p;
        double m00 = b00 * ip, m11 = b11 * ip, m22 = b22 * ip;
        double m01 = a01 * ip, m02 = a02 * ip, m12 = a12 * ip;
        double det = m00 * (m11 * m22 - m12 * m12)
                   - m01 * (m01 * m22 - m12 * m02)
                   + m02 * (m01 * m12 - m11 * m02);
        double r = 0.5 * det;
        r = r > 1.0 ? 1.0 : (r < -1.0 ? -1.0 : r);
        double phi = acos(r) * (1.0 / 3.0);
        lmin = q + 2.0 * p * cos(phi + 2.0943951023931953);
    }
    return (float)(lmin / (tr + 1e-6));
}

// ---------------- repack + per-batch raw stats -----------------------------
__global__ void prep_kernel(const float* __restrict__ xyz,
                            float* __restrict__ ws) {
    __shared__ double dstat[48];
    int b = blockIdx.x;
    int tid = threadIdx.x;
    const float* base = xyz + b * NPTS * 3;
    float4* P4 = (float4*)(ws + WS_PTS) + b * NPTS;
    double sx = 0, sy = 0, sz = 0, qxx = 0, qyy = 0, qzz = 0;
    for (int p = tid; p < NPTS; p += BLKT) {
        float x = base[p * 3], y = base[p * 3 + 1], z = base[p * 3 + 2];
        float w = __builtin_fmaf(z, z, __builtin_fmaf(y, y, x * x));
        P4[p] = make_float4(-2.0f * x, -2.0f * y, -2.0f * z, w);
        sx += (double)x; sy += (double)y; sz += (double)z;
        qxx += (double)x * x; qyy += (double)y * y; qzz += (double)z * z;
    }
    for (int off = 32; off > 0; off >>= 1) {
        sx += __shfl_down(sx, off);  sy += __shfl_down(sy, off);
        sz += __shfl_down(sz, off);  qxx += __shfl_down(qxx, off);
        qyy += __shfl_down(qyy, off); qzz += __shfl_down(qzz, off);
    }
    int wid = tid >> 6;
    if ((tid & 63) == 0) {
        dstat[wid * 6 + 0] = sx;  dstat[wid * 6 + 1] = sy;  dstat[wid * 6 + 2] = sz;
        dstat[wid * 6 + 3] = qxx; dstat[wid * 6 + 4] = qyy; dstat[wid * 6 + 5] = qzz;
    }
    __syncthreads();
    if (tid == 0) {
        double* wd = (double*)(ws + WS_STAT);
        for (int qq = 0; qq < 6; qq++) {
            double a = 0.0;
            for (int w = 0; w < 8; w++) a += dstat[w * 6 + qq];
            wd[b * 6 + qq] = a;
        }
    }
}

// ---------------- kNN + covariance + curvature + lstd ----------------------
__global__ __launch_bounds__(BLKT, 6) void knn_kernel(float* __restrict__ ws) {
    __shared__ float4 tile[TILE];                // 32 KB staged half-cloud
    __shared__ ull aux[2176];                    // 17408 B: 2 pub regions|sbuf
    unsigned char* sbuf = (unsigned char*)aux;   // [SCAP][BLKT] u8 survivors

    int b = blockIdx.x >> 7;                     // 128 chunks per batch
    int chunk = blockIdx.x & 127;
    int tid = threadIdx.x;
    int wv = tid >> 6;
    int lane = tid & 63;
    int ql = chunk * QPB + (lane & 31);          // this lane's query (local)
    const float4* __restrict__ P4 = (const float4*)(ws + WS_PTS) + b * NPTS;

    float4 qc = P4[ql];
    float qx = -0.5f * qc.x, qy = -0.5f * qc.y, qz = -0.5f * qc.z;  // exact
    int tb = wv * 256 + (lane >> 5) * LCH;       // in-tile partition base

    // ---- pass 1: branch-free med3 sorted top-17 (values only), 2 tiles ----
    float md[KNN];
#pragma unroll
    for (int k = 0; k < KNN; k++) md[k] = 3.4e38f;

    for (int t = 0; t < 2; t++) {
        __syncthreads();                         // prior tile fully consumed
        for (int p = tid; p < TILE; p += BLKT) tile[p] = P4[t * TILE + p];
        __syncthreads();
        for (int m = 0; m < LCH; m += 8) {
#pragma unroll
            for (int u = 0; u < 8; u++) {
                float4 c = tile[tb + m + u];
                float d2 = d2p(c, qx, qy, qz);
#pragma unroll
                for (int k = KNN - 1; k >= 1; k--)   // descending: reads olds
                    md[k] = __builtin_amdgcn_fmed3f(d2, md[k - 1], md[k]);
                md[0] = fminf(d2, md[0]);
            }
        }
    }
    float tau = md[KNN - 1];   // exact 17th (identical fmaf chain everywhere)

    // ---- pass 2 + drain per tile: u8 survivors -> exact u64 top-17 --------
    ull k17[KNN];
#pragma unroll
    for (int k = 0; k < KNN; k++) k17[k] = SENT;
    ull maxv = SENT; int maxp = 0;
    int cnt = 0, cprev = 0;

    for (int t = 0; t < 2; t++) {
        __syncthreads();
        for (int p = tid; p < TILE; p += BLKT) tile[p] = P4[t * TILE + p];
        __syncthreads();
        for (int m = 0; m < LCH; m += 4) {
#pragma unroll
            for (int u = 0; u < 4; u++) {
                float4 c = tile[tb + m + u];
                float d2 = d2p(c, qx, qy, qz);
                if (d2 <= tau) {                 // clamp drops latest = jax
                    if (cnt < SCAP) sbuf[cnt * BLKT + tid] = (unsigned char)(m + u);
                    cnt++;
                }
            }
        }
        // drain this tile's survivors (tile-resident, exact same d2' chain)
        int clim = cnt < SCAP ? cnt : SCAP;
#pragma unroll
        for (int s = 0; s < SCAP; s++) {
            bool act = (s >= cprev) && (s < clim);
            if (__any(act)) {
                int off = act ? (int)sbuf[s * BLKT + tid] : 0;
                float4 c = tile[tb + off];
                int ix = t * TILE + tb + off;
                float d2 = d2p(c, qx, qy, qz);
                ull key = ((ull)encf(d2) << 32) | (unsigned)ix;
                bool ins = act && (key < maxv);
                if (__any(ins)) insertp(key, ins, k17, maxv, maxp);
            }
        }
        cprev = clim;
    }

    // ---- tournament merge (full u64 key publishes, 2 regions) -------------
    // region r: aux[r*1088 + lane*17 + k]
    // round 1a: 1->0, 3->2
    __syncthreads();
    if (wv == 1 || wv == 3) {
#pragma unroll
        for (int k = 0; k < KNN; k++)
            aux[(wv >> 1) * 1088 + lane * KNN + k] = k17[k];
    }
    __syncthreads();
    if (wv == 0 || wv == 2) {
        int r = wv >> 1;
#pragma unroll
        for (int k = 0; k < KNN; k++) {
            ull key = aux[r * 1088 + lane * KNN + k];
            bool ins = key < maxv;
            if (__any(ins)) insertp(key, ins, k17, maxv, maxp);
        }
    }
    // round 1b: 5->4, 7->6
    __syncthreads();
    if (wv == 5 || wv == 7) {
#pragma unroll
        for (int k = 0; k < KNN; k++)
            aux[((wv - 4) >> 1) * 1088 + lane * KNN + k] = k17[k];
    }
    __syncthreads();
    if (wv == 4 || wv == 6) {
        int r = (wv - 4) >> 1;
#pragma unroll
        for (int k = 0; k < KNN; k++) {
            ull key = aux[r * 1088 + lane * KNN + k];
            bool ins = key < maxv;
            if (__any(ins)) insertp(key, ins, k17, maxv, maxp);
        }
    }
    // round 2: 2->0, 6->4
    __syncthreads();
    if (wv == 2 || wv == 6) {
#pragma unroll
        for (int k = 0; k < KNN; k++)
            aux[(wv >> 2) * 1088 + lane * KNN + k] = k17[k];
    }
    __syncthreads();
    if (wv == 0 || wv == 4) {
        int r = wv >> 2;
#pragma unroll
        for (int k = 0; k < KNN; k++) {
            ull key = aux[r * 1088 + lane * KNN + k];
            bool ins = key < maxv;
            if (__any(ins)) insertp(key, ins, k17, maxv, maxp);
        }
    }
    // round 3: 4->0
    __syncthreads();
    if (wv == 4) {
#pragma unroll
        for (int k = 0; k < KNN; k++) aux[lane * KNN + k] = k17[k];
    }
    __syncthreads();

    // ---- wave 0: final merge + half-merge + moments -> curv, rasig2 -------
    if (wv == 0) {
#pragma unroll
        for (int k = 0; k < KNN; k++) {
            ull key = aux[lane * KNN + k];
            bool ins = key < maxv;
            if (__any(ins)) insertp(key, ins, k17, maxv, maxp);
        }
        // half-merge: lanes 32..63 (high half-partitions) -> lanes 0..31
#pragma unroll
        for (int k = 0; k < KNN; k++) {
            ull other = __shfl(k17[k], lane ^ 32);
            bool ins = (lane < 32) && (other < maxv);
            if (__any(ins)) insertp(other, ins, k17, maxv, maxp);
        }

        float curv = 0.0f;
        if (lane < 32) {
            float s1x = 0, s1y = 0, s1z = 0;
            float cxx = 0, cxy = 0, cxz = 0, cyy = 0, cyz = 0, czz = 0;
#pragma unroll
            for (int k = 0; k < KNN; k++) {
                int j = (int)(k17[k] & 0xffffffffULL);
                float4 c = P4[j];                // L2-resident gather
                float ux = -0.5f * c.x - qx;     // exact original coords
                float uy = -0.5f * c.y - qy;
                float uz = -0.5f * c.z - qz;
                s1x += ux; s1y += uy; s1z += uz;
                cxx += ux * ux; cxy += ux * uy; cxz += ux * uz;
                cyy += uy * uy; cyz += uy * uz; czz += uz * uz;
            }
            const float i16 = 1.0f / 16.0f, i15 = 1.0f / 15.0f;
            float mx = s1x * i16, my = s1y * i16, mz = s1z * i16;
            float c00 = (cxx - 16.0f * mx * mx) * i15;
            float c01 = (cxy - 16.0f * mx * my) * i15;
            float c02 = (cxz - 16.0f * mx * mz) * i15;
            float c11 = (cyy - 16.0f * my * my) * i15;
            float c12 = (cyz - 16.0f * my * mz) * i15;
            float c22 = (czz - 16.0f * mz * mz) * i15;

            curv = curv_from_cov(c00, c01, c02, c11, c12, c22);

            float v0 = c00 > 0.0f ? c00 : 0.0f;
            float v1 = c11 > 0.0f ? c11 : 0.0f;
            float v2 = c22 > 0.0f ? c22 : 0.0f;
            float r2x = 1.0f / (0.3f * (1.0f + sqrtf(v0)) + 1e-6f);
            float r2y = 1.0f / (0.3f * (1.0f + sqrtf(v1)) + 1e-6f);
            float r2z = 1.0f / (0.3f * (1.0f + sqrtf(v2)) + 1e-6f);

            int g = b * NPTS + ql;
            ws[WS_CURV + g] = curv;
            ws[WS_RAS2 + 0 * 32768 + g] = r2x;
            ws[WS_RAS2 + 1 * 32768 + g] = r2y;
            ws[WS_RAS2 + 2 * 32768 + g] = r2z;
        }
        // non-atomic per-(b,chunk) partial sum (32 curvs; upper lanes add 0)
        float cs = curv;
        for (int off = 32; off > 0; off >>= 1) cs += __shfl_down(cs, off);
        if (lane == 0) ws[WS_CSUM + b * 128 + chunk] = cs;
    }
}

// ---------------- final embedding (scalars + cmeans per-block, parallel) ---
__global__ void out_kernel(const float* __restrict__ xyz,
                           const float* __restrict__ ws,
                           float* __restrict__ out) {
    __shared__ float sc[3];                      // rasig1, blend, 1-blend
    __shared__ float scm[8];                     // per-batch curv mean
    if (threadIdx.x < 64) {
        // gstd from double stats (24 lanes) -> sigmoid scalars
        float part = 0.0f;
        if (threadIdx.x < 24) {
            const double* st = (const double*)(ws + WS_STAT);
            int bb = threadIdx.x / 3, dd = threadIdx.x % 3;
            double s = st[bb * 6 + dd], ss = st[bb * 6 + 3 + dd];
            double var = (ss - s * s / 4096.0) / 4095.0;
            part = (float)sqrt(var > 0.0 ? var : 0.0);
        }
        float p2 = part;
        for (int off = 32; off > 0; off >>= 1) p2 += __shfl_down(p2, off);
        if (threadIdx.x == 0) {
            float gf = p2 * (1.0f / 24.0f);
            float denom = 0.3f * (1.0f + gf) + 1e-6f;
            float blend = 1.0f / (1.0f + __expf(-(gf - 0.1f) * 10.0f));
            sc[0] = 1.0f / denom;
            sc[1] = blend;
            sc[2] = 1.0f - blend;
        }
        // per-batch curv means from 1024 partials: lane L sums [L*16,L*16+16)
        float cp = 0.0f;
        const float* pf = ws + WS_CSUM;
#pragma unroll
        for (int t = 0; t < 16; t++) cp += pf[threadIdx.x * 16 + t];
        cp += __shfl_down(cp, 4);
        cp += __shfl_down(cp, 2);
        cp += __shfl_down(cp, 1);
        if ((threadIdx.x & 7) == 0) scm[threadIdx.x >> 3] = cp * (1.0f / 4096.0f);
    }
    __syncthreads();

    int idx = blockIdx.x * 256 + (int)threadIdx.x;
    int j = idx & 127;
    int g = idx >> 7;
    int b = g >> 12;
    int f = (j < 127) ? j : 128;                      // OUT_IDX
    int d = (f >= 86) ? 2 : ((f >= 43) ? 1 : 0);
    int t = f - d * 43;
    float fv = (float)((double)(t + 1) * (2.0 / 44.0) - 1.0);  // FEAT_VAL[t]

    float x = xyz[g * 3 + d];
    float rasig1 = sc[0];
    float blend  = sc[1];
    float blendc = sc[2];
    float cmean  = scm[b];
    float curv   = ws[WS_CURV + g];
    float w = 1.0f / (1.0f + __expf(-10.0f * (curv - cmean)));

    float t1 = (x - fv) * rasig1;
    float e1 = blend * __expf(-0.5f * t1 * t1) + blendc * __cosf(t1);
    float t2 = (x - fv) * ws[WS_RAS2 + (d << 15) + g];
    float e2 = __expf(-0.5f * t2 * t2);
    out[idx] = w * e1 + (1.0f - w) * e2;
}

extern "C" void kernel_launch(void* const* d_in, const int* in_sizes, int n_in,
                              void* d_out, int out_size, void* d_ws, size_t ws_size,
                              hipStream_t stream) {
    const float* xyz = (const float*)d_in[0];
    float* out = (float*)d_out;
    float* ws = (float*)d_ws;

    prep_kernel<<<8, BLKT, 0, stream>>>(xyz, ws);
    knn_kernel<<<1024, BLKT, 0, stream>>>(ws);
    out_kernel<<<out_size / 256, 256, 0, stream>>>(xyz, ws, out);
}

// Round 3
// 273.881 us; speedup vs baseline: 1.2484x; 1.2484x over previous
//
#include <hip/hip_runtime.h>
#include <math.h>

// ---------------------------------------------------------------------------
// EncoderGPECls: kNN(16) -> PCA curvature blend -> adaptive GPE embeddings
// xyz: [8,4096,3] f32  ->  out: [8,4096,128] f32
//
// R15 = R12's proven structure (216us knn) + instruction-count cuts only.
//   R13 (global-L2 stream) and R14 (staged half-tiles) both regressed ->
//   structural changes lose; revert to resident-64KB-tile, 512-thr, QPB=64,
//   u16 merge publishes, identical barriers. Grafted-in cuts (correctness
//   proven in R13/R14): (a) prep_kernel repacks points to
//   float4(-2x,-2y,-2z,|c|^2) so d2' = 3 fma (was 6 ops) -- same per-query
//   ordering, sign-flip key encoding, exact tau (no margin; margin is wrong
//   for negative d2'); (b) per-batch raw stats computed in prep_kernel ->
//   chunk-0 special case removed (uniform blocks, no tail); (c) tile staged
//   with coalesced float4 loads from the repacked buffer.
//   Selection semantics unchanged from R12: per-wave eighth, exact u64
//   (enc(d2'),idx) keys = jax lower-index tie-break; SCAP clamp drops the
//   latest-arriving = highest-index boundary tie, which is what jax drops.
//
// ws float layout:
//   [0, 32768)            curv per point
//   [32768, 131072)       rasig2 (3 SoA planes of 32768)
//   [131072, 131584)      curv partial sums [b][chunk] (8 x 64)
//   [131584, 131680)      per-batch raw sums as 48 DOUBLES
//   [131680, 262752)      repacked points: 8*4096 float4 (-2x,-2y,-2z,|c|^2)
// ---------------------------------------------------------------------------

#define NPTS 4096
#define KNN 17          // 16 neighbors + self (self contributes zero to sums)
#define BLKT 512        // 8 waves; 64 queries per block (1 per lane)
#define QPB 64
#define ESIZE 512       // candidates per wave (eighth)
#define SEG 256         // pass-2 segment size (u8 offsets)
#define SCAP 17         // survivor slots per lane per segment

#define WS_CURV  0
#define WS_RAS2  32768
#define WS_CSUM  131072
#define WS_STAT  131584
#define WS_PTS   131680

typedef unsigned long long ull;
#define SENT 0xFFFFFFFFFFFFFFFFULL

// THE single d2' definition: explicit fmaf chain, identical IEEE ops at every
// call site. c = (-2cx,-2cy,-2cz,|c|^2), q = original coords.
// d2'(c,q) = |c|^2 - 2 c.q = |c-q|^2 - |q|^2 (per-query constant offset ->
// identical ordering; can be negative). Self always ranks first.
__device__ __forceinline__ float d2p(float4 c, float qx, float qy, float qz) {
    return __builtin_fmaf(c.x, qx, __builtin_fmaf(c.y, qy,
           __builtin_fmaf(c.z, qz, c.w)));
}

// order-preserving u32 encoding of a (possibly negative) float
__device__ __forceinline__ unsigned encf(float f) {
    unsigned u = __float_as_uint(f);
    return u ^ (unsigned)(((int)u >> 31) | 0x80000000u);
}

// predicated replace-max insert of packed (enc(d2')<<32|idx) key
__device__ __forceinline__ void insertp(ull v, bool ins, ull (&md)[KNN],
                                        ull& maxv, int& maxp) {
#pragma unroll
    for (int k = 0; k < KNN; k++) {
        bool sel = ins && (k == maxp);
        md[k] = sel ? v : md[k];
    }
    maxv = md[0]; maxp = 0;
#pragma unroll
    for (int k = 1; k < KNN; k++) {
        bool g = md[k] > maxv;
        maxv = g ? md[k] : maxv;
        maxp = g ? k : maxp;
    }
}

// ---------------- 3x3 symmetric eigensolve (double, trig method) -----------
__device__ __forceinline__ float curv_from_cov(float c00, float c01, float c02,
                                               float c11, float c12, float c22) {
    double a00 = c00, a01 = c01, a02 = c02, a11 = c11, a12 = c12, a22 = c22;
    double tr = a00 + a11 + a22;
    double q  = tr * (1.0 / 3.0);
    double b00 = a00 - q, b11 = a11 - q, b22 = a22 - q;
    double p2 = b00 * b00 + b11 * b11 + b22 * b22
              + 2.0 * (a01 * a01 + a02 * a02 + a12 * a12);
    double lmin;
    if (p2 < 1e-60) {
        lmin = q;
    } else {
        double p  = sqrt(p2 * (1.0 / 6.0));
        double ip = 1.0 / p;
        double m00 = b00 * ip, m11 = b11 * ip, m22 = b22 * ip;
        double m01 = a01 * ip, m02 = a02 * ip, m12 = a12 * ip;
        double det = m00 * (m11 * m22 - m12 * m12)
                   - m01 * (m01 * m22 - m12 * m02)
                   + m02 * (m01 * m12 - m11 * m02);
        double r = 0.5 * det;
        r = r > 1.0 ? 1.0 : (r < -1.0 ? -1.0 : r);
        double phi = acos(r) * (1.0 / 3.0);
        lmin = q + 2.0 * p * cos(phi + 2.0943951023931953);
    }
    return (float)(lmin / (tr + 1e-6));
}

// ---------------- repack + per-batch raw stats -----------------------------
__global__ void prep_kernel(const float* __restrict__ xyz,
                            float* __restrict__ ws) {
    __shared__ double dstat[48];
    int b = blockIdx.x;
    int tid = threadIdx.x;
    const float* base = xyz + b * NPTS * 3;
    float4* P4 = (float4*)(ws + WS_PTS) + b * NPTS;
    double sx = 0, sy = 0, sz = 0, qxx = 0, qyy = 0, qzz = 0;
    for (int p = tid; p < NPTS; p += BLKT) {
        float x = base[p * 3], y = base[p * 3 + 1], z = base[p * 3 + 2];
        float w = __builtin_fmaf(z, z, __builtin_fmaf(y, y, x * x));
        P4[p] = make_float4(-2.0f * x, -2.0f * y, -2.0f * z, w);
        sx += (double)x; sy += (double)y; sz += (double)z;
        qxx += (double)x * x; qyy += (double)y * y; qzz += (double)z * z;
    }
    for (int off = 32; off > 0; off >>= 1) {
        sx += __shfl_down(sx, off);  sy += __shfl_down(sy, off);
        sz += __shfl_down(sz, off);  qxx += __shfl_down(qxx, off);
        qyy += __shfl_down(qyy, off); qzz += __shfl_down(qzz, off);
    }
    int wid = tid >> 6;
    if ((tid & 63) == 0) {
        dstat[wid * 6 + 0] = sx;  dstat[wid * 6 + 1] = sy;  dstat[wid * 6 + 2] = sz;
        dstat[wid * 6 + 3] = qxx; dstat[wid * 6 + 4] = qyy; dstat[wid * 6 + 5] = qzz;
    }
    __syncthreads();
    if (tid == 0) {
        double* wd = (double*)(ws + WS_STAT);
        for (int qq = 0; qq < 6; qq++) {
            double a = 0.0;
            for (int w = 0; w < 8; w++) a += dstat[w * 6 + qq];
            wd[b * 6 + qq] = a;
        }
    }
}

// ---------------- kNN + covariance + curvature + lstd ----------------------
__global__ __launch_bounds__(BLKT, 4) void knn_kernel(float* __restrict__ ws) {
    __shared__ float4 pts[NPTS];                 // 64 KB (repacked points)
    __shared__ ull aux[1088];                    // 8704 B arena (aliased)
    unsigned char* sbuf = (unsigned char*)aux;   // [SCAP][BLKT] u8 survivors
    unsigned short* pub = (unsigned short*)aux;  // 4 regions x 64x17 u16 idx
    int b = blockIdx.x >> 6;                     // 64 blocks per batch
    int chunk = blockIdx.x & 63;
    int tid = threadIdx.x;
    const float4* __restrict__ P4g = (const float4*)(ws + WS_PTS) + b * NPTS;
    for (int p = tid; p < NPTS; p += BLKT) pts[p] = P4g[p];
    __syncthreads();

    int wv = tid >> 6;                           // wave id: candidate eighth
    int lane = tid & 63;
    int i = chunk * QPB + lane;                  // this lane's query point
    float4 qc = pts[i];
    float qx = -0.5f * qc.x, qy = -0.5f * qc.y, qz = -0.5f * qc.z;  // exact
    int cbase = wv * ESIZE;                      // this wave's candidate range

    // ---- pass 1: branch-free med3 sorted top-17 (values only) -------------
    float md[KNN];
#pragma unroll
    for (int k = 0; k < KNN; k++) md[k] = 3.4e38f;

    float4 cc[4];
#pragma unroll
    for (int u = 0; u < 4; u++) cc[u] = pts[cbase + u];
    for (int m = 0; m < ESIZE; m += 4) {
        float4 cu[4];
#pragma unroll
        for (int u = 0; u < 4; u++) cu[u] = cc[u];
        int mn = (m + 4 < ESIZE) ? (m + 4) : 0;  // last prefetch redundant
#pragma unroll
        for (int u = 0; u < 4; u++) cc[u] = pts[cbase + mn + u];
#pragma unroll
        for (int u = 0; u < 4; u++) {
            float d2 = d2p(cu[u], qx, qy, qz);
#pragma unroll
            for (int k = KNN - 1; k >= 1; k--)   // descending: reads olds only
                md[k] = __builtin_amdgcn_fmed3f(d2, md[k - 1], md[k]);
            md[0] = fminf(d2, md[0]);
        }
    }
    float tau = md[KNN - 1];   // exact 17th (identical fmaf chain everywhere)

    // ---- pass 2 (2 segments of 256): u8 survivor offsets + exact select ---
    ull k17[KNN];
#pragma unroll
    for (int k = 0; k < KNN; k++) k17[k] = SENT;
    ull maxv = SENT; int maxp = 0;

#pragma unroll
    for (int sgi = 0; sgi < 2; sgi++) {
        int segbase = cbase + sgi * SEG;
        int cnt = 0;
#pragma unroll
        for (int u = 0; u < 4; u++) cc[u] = pts[segbase + u];
        for (int m = 0; m < SEG; m += 4) {
            float4 cu[4];
#pragma unroll
            for (int u = 0; u < 4; u++) cu[u] = cc[u];
            int mn = (m + 4 < SEG) ? (m + 4) : 0;
#pragma unroll
            for (int u = 0; u < 4; u++) cc[u] = pts[segbase + mn + u];
#pragma unroll
            for (int u = 0; u < 4; u++) {
                float d2 = d2p(cu[u], qx, qy, qz);
                if (d2 <= tau) {                 // clamp drops latest tie = jax
                    if (cnt < SCAP) sbuf[cnt * BLKT + tid] = (unsigned char)(m + u);
                    cnt++;
                }
            }
        }
        // drain this segment's survivors into the exact u64 top-17
#pragma unroll
        for (int t = 0; t < SCAP; t++) {
            if (__any(t < cnt)) {
                int ix = segbase + sbuf[t * BLKT + tid];
                float4 c = pts[ix];
                float d2 = d2p(c, qx, qy, qz);
                ull key = ((ull)encf(d2) << 32) | (unsigned)ix;
                bool ins = (t < cnt) && (key < maxv);
                if (__any(ins)) insertp(key, ins, k17, maxv, maxp);
            }
        }
    }

    // ---- 3-round tournament merge (u16 idx publish, keys rebuilt exactly) --
    // regions: r * 1088 u16 entries, entry lane*17+k
    // round 1: 1->0, 3->2, 5->4, 7->6   (regions 0..3)
    __syncthreads();
    if (wv & 1) {
#pragma unroll
        for (int k = 0; k < KNN; k++)
            pub[(wv >> 1) * 1088 + lane * KNN + k] = (unsigned short)(k17[k] & 0xffffULL);
    }
    __syncthreads();
    if (!(wv & 1)) {
        int r = wv >> 1;
#pragma unroll
        for (int k = 0; k < KNN; k++) {
            int ix = pub[r * 1088 + lane * KNN + k];
            float4 c = pts[ix];
            float d2 = d2p(c, qx, qy, qz);
            ull key = ((ull)encf(d2) << 32) | (unsigned)ix;
            bool ins = key < maxv;
            if (__any(ins)) insertp(key, ins, k17, maxv, maxp);
        }
    }
    // round 2: 2->0, 6->4 (regions 0,1)
    __syncthreads();
    if (wv == 2 || wv == 6) {
#pragma unroll
        for (int k = 0; k < KNN; k++)
            pub[(wv >> 2) * 1088 + lane * KNN + k] = (unsigned short)(k17[k] & 0xffffULL);
    }
    __syncthreads();
    if (wv == 0 || wv == 4) {
        int r = wv >> 2;
#pragma unroll
        for (int k = 0; k < KNN; k++) {
            int ix = pub[r * 1088 + lane * KNN + k];
            float4 c = pts[ix];
            float d2 = d2p(c, qx, qy, qz);
            ull key = ((ull)encf(d2) << 32) | (unsigned)ix;
            bool ins = key < maxv;
            if (__any(ins)) insertp(key, ins, k17, maxv, maxp);
        }
    }
    // round 3: 4->0 (region 0)
    __syncthreads();
    if (wv == 4) {
#pragma unroll
        for (int k = 0; k < KNN; k++)
            pub[lane * KNN + k] = (unsigned short)(k17[k] & 0xffffULL);
    }
    __syncthreads();

    // ---- epilogue on wave 0: final merge + moments -> curv, rasig2 --------
    if (wv == 0) {
#pragma unroll
        for (int k = 0; k < KNN; k++) {
            int ix = pub[lane * KNN + k];
            float4 c = pts[ix];
            float d2 = d2p(c, qx, qy, qz);
            ull key = ((ull)encf(d2) << 32) | (unsigned)ix;
            bool ins = key < maxv;
            if (__any(ins)) insertp(key, ins, k17, maxv, maxp);
        }

        float s1x = 0, s1y = 0, s1z = 0;
        float cxx = 0, cxy = 0, cxz = 0, cyy = 0, cyz = 0, czz = 0;
#pragma unroll
        for (int k = 0; k < KNN; k++) {
            int j = (int)(k17[k] & 0xffffffffULL);
            float4 c = pts[j];
            float ux = -0.5f * c.x - qx;         // exact original coords
            float uy = -0.5f * c.y - qy;
            float uz = -0.5f * c.z - qz;
            s1x += ux; s1y += uy; s1z += uz;
            cxx += ux * ux; cxy += ux * uy; cxz += ux * uz;
            cyy += uy * uy; cyz += uy * uz; czz += uz * uz;
        }
        const float i16 = 1.0f / 16.0f, i15 = 1.0f / 15.0f;
        float mx = s1x * i16, my = s1y * i16, mz = s1z * i16;
        float c00 = (cxx - 16.0f * mx * mx) * i15;
        float c01 = (cxy - 16.0f * mx * my) * i15;
        float c02 = (cxz - 16.0f * mx * mz) * i15;
        float c11 = (cyy - 16.0f * my * my) * i15;
        float c12 = (cyz - 16.0f * my * mz) * i15;
        float c22 = (czz - 16.0f * mz * mz) * i15;

        float curv = curv_from_cov(c00, c01, c02, c11, c12, c22);

        float v0 = c00 > 0.0f ? c00 : 0.0f;
        float v1 = c11 > 0.0f ? c11 : 0.0f;
        float v2 = c22 > 0.0f ? c22 : 0.0f;
        float r2x = 1.0f / (0.3f * (1.0f + sqrtf(v0)) + 1e-6f);
        float r2y = 1.0f / (0.3f * (1.0f + sqrtf(v1)) + 1e-6f);
        float r2z = 1.0f / (0.3f * (1.0f + sqrtf(v2)) + 1e-6f);

        int g = b * NPTS + i;
        ws[WS_CURV + g] = curv;
        ws[WS_RAS2 + 0 * 32768 + g] = r2x;
        ws[WS_RAS2 + 1 * 32768 + g] = r2y;
        ws[WS_RAS2 + 2 * 32768 + g] = r2z;

        // non-atomic per-(b,chunk) partial sum (no memset dispatch needed)
        float cs = curv;
        for (int off = 32; off > 0; off >>= 1) cs += __shfl_down(cs, off);
        if (lane == 0) ws[WS_CSUM + b * 64 + chunk] = cs;
    }
}

// ---------------- final embedding (scalars + cmeans per-block, parallel) ---
__global__ void out_kernel(const float* __restrict__ xyz,
                           const float* __restrict__ ws,
                           float* __restrict__ out) {
    __shared__ float sc[3];                      // rasig1, blend, 1-blend
    __shared__ float scm[8];                     // per-batch curv mean
    if (threadIdx.x < 64) {
        // gstd from double stats (24 lanes) -> sigmoid scalars
        float part = 0.0f;
        if (threadIdx.x < 24) {
            const double* st = (const double*)(ws + WS_STAT);
            int bb = threadIdx.x / 3, dd = threadIdx.x % 3;
            double s = st[bb * 6 + dd], ss = st[bb * 6 + 3 + dd];
            double var = (ss - s * s / 4096.0) / 4095.0;
            part = (float)sqrt(var > 0.0 ? var : 0.0);
        }
        float p2 = part;
        for (int off = 32; off > 0; off >>= 1) p2 += __shfl_down(p2, off);
        if (threadIdx.x == 0) {
            float gf = p2 * (1.0f / 24.0f);
            float denom = 0.3f * (1.0f + gf) + 1e-6f;
            float blend = 1.0f / (1.0f + __expf(-(gf - 0.1f) * 10.0f));
            sc[0] = 1.0f / denom;
            sc[1] = blend;
            sc[2] = 1.0f - blend;
        }
        // per-batch curv means from 512 partials: lane L sums [L*8, L*8+8)
        float cp = 0.0f;
        const float* pf = ws + WS_CSUM;
#pragma unroll
        for (int t = 0; t < 8; t++) cp += pf[threadIdx.x * 8 + t];
        cp += __shfl_down(cp, 4);
        cp += __shfl_down(cp, 2);
        cp += __shfl_down(cp, 1);
        if ((threadIdx.x & 7) == 0) scm[threadIdx.x >> 3] = cp * (1.0f / 4096.0f);
    }
    __syncthreads();

    int idx = blockIdx.x * 256 + (int)threadIdx.x;
    int j = idx & 127;
    int g = idx >> 7;
    int b = g >> 12;
    int f = (j < 127) ? j : 128;                      // OUT_IDX
    int d = (f >= 86) ? 2 : ((f >= 43) ? 1 : 0);
    int t = f - d * 43;
    float fv = (float)((double)(t + 1) * (2.0 / 44.0) - 1.0);  // FEAT_VAL[t]

    float x = xyz[g * 3 + d];
    float rasig1 = sc[0];
    float blend  = sc[1];
    float blendc = sc[2];
    float cmean  = scm[b];
    float curv   = ws[WS_CURV + g];
    float w = 1.0f / (1.0f + __expf(-10.0f * (curv - cmean)));

    float t1 = (x - fv) * rasig1;
    float e1 = blend * __expf(-0.5f * t1 * t1) + blendc * __cosf(t1);
    float t2 = (x - fv) * ws[WS_RAS2 + (d << 15) + g];
    float e2 = __expf(-0.5f * t2 * t2);
    out[idx] = w * e1 + (1.0f - w) * e2;
}

extern "C" void kernel_launch(void* const* d_in, const int* in_sizes, int n_in,
                              void* d_out, int out_size, void* d_ws, size_t ws_size,
                              hipStream_t stream) {
    const float* xyz = (const float*)d_in[0];
    float* out = (float*)d_out;
    float* ws = (float*)d_ws;

    prep_kernel<<<8, BLKT, 0, stream>>>(xyz, ws);
    knn_kernel<<<512, BLKT, 0, stream>>>(ws);
    out_kernel<<<out_size / 256, 256, 0, stream>>>(xyz, ws, out);
}